// Round 9
// baseline (740.098 us; speedup 1.0000x reference)
//
#include <hip/hip_runtime.h>
#include <hip/hip_bf16.h>

// Problem dims
#define V    50257
#define VPAD 50304          // padded vocab rows (786*64)
#define DD   128
#define HH   256
#define G3   768            // 3*H
#define BB   16
#define TT   128

typedef _Float16 h2   __attribute__((ext_vector_type(2)));
typedef _Float16 h8   __attribute__((ext_vector_type(8)));
typedef short  bf16x8 __attribute__((ext_vector_type(8)));
typedef float  f32x4  __attribute__((ext_vector_type(4)));

typedef __attribute__((address_space(3))) uint4* lds_u4_t;
typedef const __attribute__((address_space(1))) uint4* gbl_u4_t;

__device__ __forceinline__ void async_copy16(const uint4* g, uint4* lds_base) {
    // LDS dest = wave-uniform base + lane*16 (per-lane global scatter is OK)
    __builtin_amdgcn_global_load_lds((gbl_u4_t)g, (lds_u4_t)lds_base, 16, 0, 0);
}

#if __has_builtin(__builtin_amdgcn_fdot2)
#define USE_FDOT2 1
#else
#define USE_FDOT2 0
#endif

__device__ __forceinline__ float sigmoid_(float x) { return 1.0f / (1.0f + __expf(-x)); }
__device__ __forceinline__ float tanh_(float x)    { float e = __expf(2.0f * x); return (e - 1.0f) / (e + 1.0f); }

__device__ __forceinline__ float fdot2_(h2 a, h2 b, float c) {
#if USE_FDOT2
    return __builtin_amdgcn_fdot2(a, b, c, false);
#else
    return c + (float)a.x * (float)b.x + (float)a.y * (float)b.y;
#endif
}

// LDS-only barrier: lgkmcnt(0) (DS ops visible) + raw s_barrier. Does NOT
// drain vmcnt -> global loads/stores stay in flight across steps.
#define BARRIER_LDS() do {                                        \
    asm volatile("s_waitcnt lgkmcnt(0)" ::: "memory");            \
    __builtin_amdgcn_s_barrier();                                 \
    __builtin_amdgcn_sched_barrier(0);                            \
} while (0)

// ---------------------------------------------------------------------------
// Kernel P (merged): blocks [0,256):      x = embed[ids]; gx = x@W_ih^T + b_ih
//                    blocks [256,6544):   W_out fp32 -> bf16 padded
//                    blocks [6544,6640):  W_hh  fp32 -> f16 row-major
// ---------------------------------------------------------------------------
__global__ __launch_bounds__(256) void k_prep(
    const int* __restrict__ ids, const float* __restrict__ embed,
    const float* __restrict__ W_ih, const float* __restrict__ b_ih,
    float* __restrict__ gx,
    const float* __restrict__ Wout, __hip_bfloat16* __restrict__ Wb,
    const float* __restrict__ W_hh, _Float16* __restrict__ Wh)
{
    __shared__ float xs[8][DD];
    const int tid = threadIdx.x;

    if (blockIdx.x >= 6544) {
        // ---- W_hh fp32 -> f16 path: 96 blocks x 256 thr x 8 = 196608 exact --
        long base = ((long)(blockIdx.x - 6544) * 256 + tid) * 8;
        float4 f0 = ((const float4*)W_hh)[base / 4];
        float4 f1 = ((const float4*)W_hh)[base / 4 + 1];
        union { _Float16 h[8]; uint4 u; } pk;
        pk.h[0] = (_Float16)f0.x; pk.h[1] = (_Float16)f0.y;
        pk.h[2] = (_Float16)f0.z; pk.h[3] = (_Float16)f0.w;
        pk.h[4] = (_Float16)f1.x; pk.h[5] = (_Float16)f1.y;
        pk.h[6] = (_Float16)f1.z; pk.h[7] = (_Float16)f1.w;
        *(uint4*)(Wh + base) = pk.u;
        return;
    }

    if (blockIdx.x >= 256) {
        // ---- W_out conversion path ----
        long base = ((long)(blockIdx.x - 256) * 256 + tid) * 8;
        const long VALID = (long)V * HH;   // 12,865,792 (divisible by 8)
        union { __hip_bfloat16 b[8]; uint4 u; } pk;
        if (base < VALID) {
            float4 f0 = ((const float4*)Wout)[base / 4];
            float4 f1 = ((const float4*)Wout)[base / 4 + 1];
            pk.b[0] = __float2bfloat16(f0.x); pk.b[1] = __float2bfloat16(f0.y);
            pk.b[2] = __float2bfloat16(f0.z); pk.b[3] = __float2bfloat16(f0.w);
            pk.b[4] = __float2bfloat16(f1.x); pk.b[5] = __float2bfloat16(f1.y);
            pk.b[6] = __float2bfloat16(f1.z); pk.b[7] = __float2bfloat16(f1.w);
        } else {
            pk.u = make_uint4(0, 0, 0, 0);
        }
        *(uint4*)(Wb + base) = pk.u;
        return;
    }

    // ---- embed + gx path ----
    const int row0 = blockIdx.x * 8;

#pragma unroll
    for (int i = 0; i < 4; ++i) {
        int e = tid + i * 256;
        int r = e >> 7, k = e & 127;
        int id = ids[row0 + r];
        xs[r][k] = embed[(long)id * DD + k];
    }
    __syncthreads();

#pragma unroll
    for (int o = 0; o < 3; ++o) {
        int j = tid + o * 256;
        float bias = b_ih[j];
        float acc[8];
#pragma unroll
        for (int r = 0; r < 8; ++r) acc[r] = bias;
        const float4* wrow = (const float4*)(W_ih + (long)j * DD);
        for (int q = 0; q < 32; ++q) {
            float4 w = wrow[q];
#pragma unroll
            for (int r = 0; r < 8; ++r) {
                acc[r] += w.x * xs[r][q * 4 + 0] + w.y * xs[r][q * 4 + 1]
                        + w.z * xs[r][q * 4 + 2] + w.w * xs[r][q * 4 + 3];
            }
        }
#pragma unroll
        for (int r = 0; r < 8; ++r) gx[(long)(row0 + r) * G3 + j] = acc[r];
    }
}

// ---------------------------------------------------------------------------
// Kernel G: GRU recurrence (round-8 configuration, byte-identical).
// Pre-converted f16 W, 512 thr K-split-2, gx chunk-staged, counted vmcnt,
// LDS-only barriers, one barrier/step. Measured G ~= 140us.
// ---------------------------------------------------------------------------
#define CH   8      // steps per gx chunk
#define NCH  16     // chunks (CH*NCH = TT)

__global__ __launch_bounds__(512)
__attribute__((amdgpu_waves_per_eu(2, 2)))
void k_gru(
    const float* __restrict__ gx, const _Float16* __restrict__ Wh,
    const float* __restrict__ b_hh, __hip_bfloat16* __restrict__ hout)
{
    __shared__ float    gxs[2][CH][G3];   // 48 KB double-buffered gx chunks
    __shared__ _Float16 hh[2][HH];        // double-buffered hidden state

    const int tid = threadIdx.x;
    const int b   = blockIdx.x;      // batch
    const int g   = tid >> 1;        // output row within each gate [0,256)
    const int u   = tid & 1;         // K-half
    const int wv  = tid >> 6;        // wave [0,8)
    const int ln  = tid & 63;        // lane

    // W_hh rows {g, 256+g, 512+g}, K-half u: 3 x 16 h8 = 192 VGPRs.
    h8 w8[3][16];
#pragma unroll
    for (int o = 0; o < 3; ++o) {
        const h8* wrow = (const h8*)(Wh + (long)(o * HH + g) * HH + u * 128);
#pragma unroll
        for (int q = 0; q < 16; ++q) w8[o][q] = wrow[q];
    }
    float bias[3];
#pragma unroll
    for (int o = 0; o < 3; ++o) bias[o] = b_hh[o * HH + g];

    if (tid < HH) hh[0][tid] = (_Float16)0.0f;

    const float* gxb = gx + (long)b * TT * G3;
    // stage chunk c (24KB = 1536 uint4) into buffer buf: 3 x 64 lanes per wave
    auto stage = [&](int c, int buf) {
        const uint4* src = (const uint4*)(gxb + (long)c * CH * G3);
        uint4* dstb = (uint4*)(&gxs[buf][0][0]);
#pragma unroll
        for (int k = 0; k < 3; ++k)
            async_copy16(src + (wv * 3 + k) * 64 + ln, dstb + (wv * 3 + k) * 64);
    };

    stage(0, 0);
    float hold = 0.0f;

    for (int c = 0; c < NCH; ++c) {
        const int buf = c & 1;
        if (c + 1 < NCH) {
            stage(c + 1, buf ^ 1);
            asm volatile("s_waitcnt vmcnt(3)" ::: "memory");
        } else {
            asm volatile("s_waitcnt vmcnt(0)" ::: "memory");
        }
        BARRIER_LDS();   // chunk c visible (+ hh[0] init at c=0)

        for (int s = 0; s < CH; ++s) {
            const int t = c * CH + s;
            float xr = gxs[buf][s][g];
            float xz = gxs[buf][s][HH + g];
            float xn = gxs[buf][s][2 * HH + g];

            float a0a = 0.f, a0b = 0.f, a1a = 0.f, a1b = 0.f, a2a = 0.f, a2b = 0.f;
            const h8* hp8 = ((const h8*)hh[t & 1]) + u * 16;
#pragma unroll
            for (int q = 0; q < 16; ++q) {
                h8 hv = hp8[q];
                const h2* hq = (const h2*)&hv;
                const h2* w0 = (const h2*)&w8[0][q];
                const h2* w1 = (const h2*)&w8[1][q];
                const h2* w2 = (const h2*)&w8[2][q];
#pragma unroll
                for (int jj = 0; jj < 4; ++jj) {
                    if (jj & 1) {
                        a0b = fdot2_(w0[jj], hq[jj], a0b);
                        a1b = fdot2_(w1[jj], hq[jj], a1b);
                        a2b = fdot2_(w2[jj], hq[jj], a2b);
                    } else {
                        a0a = fdot2_(w0[jj], hq[jj], a0a);
                        a1a = fdot2_(w1[jj], hq[jj], a1a);
                        a2a = fdot2_(w2[jj], hq[jj], a2a);
                    }
                }
            }
            float acc0 = a0a + a0b, acc1 = a1a + a1b, acc2 = a2a + a2b;
            acc0 += __shfl_xor(acc0, 1);
            acc1 += __shfl_xor(acc1, 1);
            acc2 += __shfl_xor(acc2, 1);

            float r = sigmoid_(xr + acc0 + bias[0]);
            float z = sigmoid_(xz + acc1 + bias[1]);
            float n = tanh_(xn + r * (acc2 + bias[2]));
            float hnew = (1.0f - z) * n + z * hold;

            if (u == 0) hh[(t + 1) & 1][g] = (_Float16)hnew;
            else        hout[((long)b * TT + t) * HH + g] = __float2bfloat16(hnew);
            BARRIER_LDS();   // next h buffer ready; one barrier per step

            hold = hnew;
        }
    }
}

// ---------------------------------------------------------------------------
// Kernel C: LM head GEMM. C[2048,50257] = A[2048,256] * B[50304,256]^T, bf16
// MFMA 16x16x32. ROUND-9: BM=256, BN=64, BK=64, 256 threads. 4 waves stacked
// VERTICALLY (each wave owns a 64x64 sub-tile -> per-wave inner loop and
// register profile identical to the proven 128x128 kernel).
// Rationale: head moves 412MB C-writes (HBM) + B-panel re-reads (L3). With
// BM=128 the B panel was re-read 16x = 412MB; BM=256 cuts that to 8x =
// 206MB. A tile grows to 128KB/block but A total is 1MB -> pure L2 hits
// (free). LDS 40KB -> 4 blocks/CU unchanged. MFMA accumulation order per
// output element unchanged -> bit-identical results.
// ---------------------------------------------------------------------------
__global__ __launch_bounds__(256) void k_head(
    const __hip_bfloat16* __restrict__ Ah, const __hip_bfloat16* __restrict__ Bw,
    float* __restrict__ out)
{
    __shared__ unsigned short As[256 * 64];   // 32KB: 256 rows x 8 slots x 8 bf16
    __shared__ unsigned short Bs[64 * 64];    //  8KB:  64 rows x 8 slots x 8 bf16
    const int i    = threadIdx.x;
    const int wave = i >> 6, lane = i & 63;
    const int quad = lane >> 4, mr = lane & 15;
    const int n0   = blockIdx.x * 64;         // 786 n-tiles
    const int m0   = blockIdx.y * 256;        // 8 m-tiles
    const int wm0  = wave * 64;               // waves stacked vertically

    f32x4 acc[4][4];
#pragma unroll
    for (int a = 0; a < 4; ++a)
#pragma unroll
        for (int c = 0; c < 4; ++c) acc[a][c] = (f32x4){0.f, 0.f, 0.f, 0.f};

    const uint4* Ag = (const uint4*)Ah;   // row = 32 uint4 (256 bf16)
    const uint4* Bg = (const uint4*)Bw;
    uint4* Asv = (uint4*)As;
    uint4* Bsv = (uint4*)Bs;

    // Staging geometry. A: 32 segments of 8 rows (seg = c*4 + wave, c<8);
    // B: 8 segments (seg = c*4 + wave, c<2). Within a segment, lane covers
    // row seg*8 + (lane>>3), 16B-chunk (lane&7)^(row&7); row&7 == lane>>3.
    const int lrow = lane >> 3;
    const int lchk = (lane & 7) ^ lrow;

    const uint4* agp[8]; uint4* alds[8];
#pragma unroll
    for (int c = 0; c < 8; ++c) {
        int seg = c * 4 + wave;
        agp[c]  = Ag + (long)(m0 + seg * 8 + lrow) * 32 + lchk;
        alds[c] = Asv + seg * 64;
    }
    const uint4* bgp[2]; uint4* blds[2];
#pragma unroll
    for (int c = 0; c < 2; ++c) {
        int seg = c * 4 + wave;
        bgp[c]  = Bg + (long)(n0 + seg * 8 + lrow) * 32 + lchk;
        blds[c] = Bsv + seg * 64;
    }

    for (int ks = 0; ks < 4; ++ks) {
        __syncthreads();   // previous iteration's LDS readers done
#pragma unroll
        for (int c = 0; c < 8; ++c) async_copy16(agp[c] + ks * 8, alds[c]);
#pragma unroll
        for (int c = 0; c < 2; ++c) async_copy16(bgp[c] + ks * 8, blds[c]);
        __syncthreads();   // compiler emits s_waitcnt vmcnt(0) before barrier

#pragma unroll
        for (int kk = 0; kk < 2; ++kk) {
            const int slot = (kk * 4 + quad) ^ (mr & 7);
            bf16x8 af[4], bf[4];
#pragma unroll
            for (int wmi = 0; wmi < 4; ++wmi) {
                int row = wm0 + wmi * 16 + mr;        // row&7 == mr&7
                af[wmi] = *(const bf16x8*)&As[(row * 8 + slot) * 8];
            }
#pragma unroll
            for (int wni = 0; wni < 4; ++wni) {
                int row = wni * 16 + mr;              // row&7 == mr&7
                bf[wni] = *(const bf16x8*)&Bs[(row * 8 + slot) * 8];
            }
#pragma unroll
            for (int wmi = 0; wmi < 4; ++wmi)
#pragma unroll
                for (int wni = 0; wni < 4; ++wni)
                    acc[wmi][wni] = __builtin_amdgcn_mfma_f32_16x16x32_bf16(
                        af[wmi], bf[wni], acc[wmi][wni], 0, 0, 0);
        }
    }

    // epilogue: C/D layout col = lane&15, row = quad*4 + reg
#pragma unroll
    for (int wmi = 0; wmi < 4; ++wmi) {
#pragma unroll
        for (int rr = 0; rr < 4; ++rr) {
            long m = m0 + wm0 + wmi * 16 + quad * 4 + rr;
            float* orow = out + m * (long)V;
#pragma unroll
            for (int wni = 0; wni < 4; ++wni) {
                int n = n0 + wni * 16 + mr;
                if (n < V) orow[n] = acc[wmi][wni][rr];
            }
        }
    }
}

// ---------------------------------------------------------------------------
extern "C" void kernel_launch(void* const* d_in, const int* in_sizes, int n_in,
                              void* d_out, int out_size, void* d_ws, size_t ws_size,
                              hipStream_t stream) {
    const int*   ids   = (const int*)d_in[0];
    const float* embed = (const float*)d_in[1];
    const float* W_ih  = (const float*)d_in[2];
    const float* b_ih  = (const float*)d_in[3];
    const float* W_hh  = (const float*)d_in[4];
    const float* b_hh  = (const float*)d_in[5];
    const float* W_out = (const float*)d_in[6];
    float* out = (float*)d_out;

    // workspace layout (ws re-poisoned each launch; everything rewritten here)
    char* ws = (char*)d_ws;
    float*          gx   = (float*)ws;                          // 2048*768*4   = 6,291,456 B
    __hip_bfloat16* hbf  = (__hip_bfloat16*)(ws + 6291456);     // 2048*256*2   = 1,048,576 B
    __hip_bfloat16* wbf  = (__hip_bfloat16*)(ws + 7340032);     // 50304*256*2  = 25,755,648 B
    _Float16*       wh16 = (_Float16*)(ws + 33095680);          // 768*256*2    = 393,216 B

    k_prep<<<6640, 256, 0, stream>>>(ids, embed, W_ih, b_ih, gx, W_out, wbf, W_hh, wh16);
    k_gru<<<16, 512, 0, stream>>>(gx, wh16, b_hh, hbf);
    k_head<<<dim3(786, 8), 256, 0, stream>>>(hbf, wbf, out);
}

// Round 10
// 722.791 us; speedup vs baseline: 1.0239x; 1.0239x over previous
//
#include <hip/hip_runtime.h>
#include <hip/hip_bf16.h>

// Problem dims
#define V    50257
#define VPAD 50304          // padded vocab rows for clean 128-tiles (393*128)
#define DD   128
#define HH   256
#define G3   768            // 3*H
#define BB   16
#define TT   128

typedef _Float16 h2   __attribute__((ext_vector_type(2)));
typedef _Float16 h8   __attribute__((ext_vector_type(8)));
typedef short  bf16x8 __attribute__((ext_vector_type(8)));
typedef float  f32x4  __attribute__((ext_vector_type(4)));

typedef __attribute__((address_space(3))) uint4* lds_u4_t;
typedef const __attribute__((address_space(1))) uint4* gbl_u4_t;

__device__ __forceinline__ void async_copy16(const uint4* g, uint4* lds_base) {
    // LDS dest = wave-uniform base + lane*16 (per-lane global scatter is OK)
    __builtin_amdgcn_global_load_lds((gbl_u4_t)g, (lds_u4_t)lds_base, 16, 0, 0);
}

#if __has_builtin(__builtin_amdgcn_fdot2)
#define USE_FDOT2 1
#else
#define USE_FDOT2 0
#endif

__device__ __forceinline__ float sigmoid_(float x) { return 1.0f / (1.0f + __expf(-x)); }
__device__ __forceinline__ float tanh_(float x)    { float e = __expf(2.0f * x); return (e - 1.0f) / (e + 1.0f); }

__device__ __forceinline__ float fdot2_(h2 a, h2 b, float c) {
#if USE_FDOT2
    return __builtin_amdgcn_fdot2(a, b, c, false);
#else
    return c + (float)a.x * (float)b.x + (float)a.y * (float)b.y;
#endif
}

// LDS-only barrier: lgkmcnt(0) (DS ops visible) + raw s_barrier. Does NOT
// drain vmcnt -> global loads/stores stay in flight across steps.
#define BARRIER_LDS() do {                                        \
    asm volatile("s_waitcnt lgkmcnt(0)" ::: "memory");            \
    __builtin_amdgcn_s_barrier();                                 \
    __builtin_amdgcn_sched_barrier(0);                            \
} while (0)

// ---------------------------------------------------------------------------
// Kernel P (merged): blocks [0,256):      x = embed[ids]; gx = x@W_ih^T + b_ih
//                    blocks [256,6544):   W_out fp32 -> bf16 padded
//                    blocks [6544,6640):  W_hh  fp32 -> f16 row-major
// ---------------------------------------------------------------------------
__global__ __launch_bounds__(256) void k_prep(
    const int* __restrict__ ids, const float* __restrict__ embed,
    const float* __restrict__ W_ih, const float* __restrict__ b_ih,
    float* __restrict__ gx,
    const float* __restrict__ Wout, __hip_bfloat16* __restrict__ Wb,
    const float* __restrict__ W_hh, _Float16* __restrict__ Wh)
{
    __shared__ float xs[8][DD];
    const int tid = threadIdx.x;

    if (blockIdx.x >= 6544) {
        // ---- W_hh fp32 -> f16 path: 96 blocks x 256 thr x 8 = 196608 exact --
        long base = ((long)(blockIdx.x - 6544) * 256 + tid) * 8;
        float4 f0 = ((const float4*)W_hh)[base / 4];
        float4 f1 = ((const float4*)W_hh)[base / 4 + 1];
        union { _Float16 h[8]; uint4 u; } pk;
        pk.h[0] = (_Float16)f0.x; pk.h[1] = (_Float16)f0.y;
        pk.h[2] = (_Float16)f0.z; pk.h[3] = (_Float16)f0.w;
        pk.h[4] = (_Float16)f1.x; pk.h[5] = (_Float16)f1.y;
        pk.h[6] = (_Float16)f1.z; pk.h[7] = (_Float16)f1.w;
        *(uint4*)(Wh + base) = pk.u;
        return;
    }

    if (blockIdx.x >= 256) {
        // ---- W_out conversion path ----
        long base = ((long)(blockIdx.x - 256) * 256 + tid) * 8;
        const long VALID = (long)V * HH;   // 12,865,792 (divisible by 8)
        union { __hip_bfloat16 b[8]; uint4 u; } pk;
        if (base < VALID) {
            float4 f0 = ((const float4*)Wout)[base / 4];
            float4 f1 = ((const float4*)Wout)[base / 4 + 1];
            pk.b[0] = __float2bfloat16(f0.x); pk.b[1] = __float2bfloat16(f0.y);
            pk.b[2] = __float2bfloat16(f0.z); pk.b[3] = __float2bfloat16(f0.w);
            pk.b[4] = __float2bfloat16(f1.x); pk.b[5] = __float2bfloat16(f1.y);
            pk.b[6] = __float2bfloat16(f1.z); pk.b[7] = __float2bfloat16(f1.w);
        } else {
            pk.u = make_uint4(0, 0, 0, 0);
        }
        *(uint4*)(Wb + base) = pk.u;
        return;
    }

    // ---- embed + gx path ----
    const int row0 = blockIdx.x * 8;

#pragma unroll
    for (int i = 0; i < 4; ++i) {
        int e = tid + i * 256;
        int r = e >> 7, k = e & 127;
        int id = ids[row0 + r];
        xs[r][k] = embed[(long)id * DD + k];
    }
    __syncthreads();

#pragma unroll
    for (int o = 0; o < 3; ++o) {
        int j = tid + o * 256;
        float bias = b_ih[j];
        float acc[8];
#pragma unroll
        for (int r = 0; r < 8; ++r) acc[r] = bias;
        const float4* wrow = (const float4*)(W_ih + (long)j * DD);
        for (int q = 0; q < 32; ++q) {
            float4 w = wrow[q];
#pragma unroll
            for (int r = 0; r < 8; ++r) {
                acc[r] += w.x * xs[r][q * 4 + 0] + w.y * xs[r][q * 4 + 1]
                        + w.z * xs[r][q * 4 + 2] + w.w * xs[r][q * 4 + 3];
            }
        }
#pragma unroll
        for (int r = 0; r < 8; ++r) gx[(long)(row0 + r) * G3 + j] = acc[r];
    }
}

// ---------------------------------------------------------------------------
// Kernel G: GRU recurrence (round-8 configuration, byte-identical).
// Pre-converted f16 W, 512 thr K-split-2, gx chunk-staged, counted vmcnt,
// LDS-only barriers, one barrier/step. Measured G ~= 140us.
// ---------------------------------------------------------------------------
#define CH   8      // steps per gx chunk
#define NCH  16     // chunks (CH*NCH = TT)

__global__ __launch_bounds__(512)
__attribute__((amdgpu_waves_per_eu(2, 2)))
void k_gru(
    const float* __restrict__ gx, const _Float16* __restrict__ Wh,
    const float* __restrict__ b_hh, __hip_bfloat16* __restrict__ hout)
{
    __shared__ float    gxs[2][CH][G3];   // 48 KB double-buffered gx chunks
    __shared__ _Float16 hh[2][HH];        // double-buffered hidden state

    const int tid = threadIdx.x;
    const int b   = blockIdx.x;      // batch
    const int g   = tid >> 1;        // output row within each gate [0,256)
    const int u   = tid & 1;         // K-half
    const int wv  = tid >> 6;        // wave [0,8)
    const int ln  = tid & 63;        // lane

    // W_hh rows {g, 256+g, 512+g}, K-half u: 3 x 16 h8 = 192 VGPRs.
    h8 w8[3][16];
#pragma unroll
    for (int o = 0; o < 3; ++o) {
        const h8* wrow = (const h8*)(Wh + (long)(o * HH + g) * HH + u * 128);
#pragma unroll
        for (int q = 0; q < 16; ++q) w8[o][q] = wrow[q];
    }
    float bias[3];
#pragma unroll
    for (int o = 0; o < 3; ++o) bias[o] = b_hh[o * HH + g];

    if (tid < HH) hh[0][tid] = (_Float16)0.0f;

    const float* gxb = gx + (long)b * TT * G3;
    // stage chunk c (24KB = 1536 uint4) into buffer buf: 3 x 64 lanes per wave
    auto stage = [&](int c, int buf) {
        const uint4* src = (const uint4*)(gxb + (long)c * CH * G3);
        uint4* dstb = (uint4*)(&gxs[buf][0][0]);
#pragma unroll
        for (int k = 0; k < 3; ++k)
            async_copy16(src + (wv * 3 + k) * 64 + ln, dstb + (wv * 3 + k) * 64);
    };

    stage(0, 0);
    float hold = 0.0f;

    for (int c = 0; c < NCH; ++c) {
        const int buf = c & 1;
        if (c + 1 < NCH) {
            stage(c + 1, buf ^ 1);
            asm volatile("s_waitcnt vmcnt(3)" ::: "memory");
        } else {
            asm volatile("s_waitcnt vmcnt(0)" ::: "memory");
        }
        BARRIER_LDS();   // chunk c visible (+ hh[0] init at c=0)

        for (int s = 0; s < CH; ++s) {
            const int t = c * CH + s;
            float xr = gxs[buf][s][g];
            float xz = gxs[buf][s][HH + g];
            float xn = gxs[buf][s][2 * HH + g];

            float a0a = 0.f, a0b = 0.f, a1a = 0.f, a1b = 0.f, a2a = 0.f, a2b = 0.f;
            const h8* hp8 = ((const h8*)hh[t & 1]) + u * 16;
#pragma unroll
            for (int q = 0; q < 16; ++q) {
                h8 hv = hp8[q];
                const h2* hq = (const h2*)&hv;
                const h2* w0 = (const h2*)&w8[0][q];
                const h2* w1 = (const h2*)&w8[1][q];
                const h2* w2 = (const h2*)&w8[2][q];
#pragma unroll
                for (int jj = 0; jj < 4; ++jj) {
                    if (jj & 1) {
                        a0b = fdot2_(w0[jj], hq[jj], a0b);
                        a1b = fdot2_(w1[jj], hq[jj], a1b);
                        a2b = fdot2_(w2[jj], hq[jj], a2b);
                    } else {
                        a0a = fdot2_(w0[jj], hq[jj], a0a);
                        a1a = fdot2_(w1[jj], hq[jj], a1a);
                        a2a = fdot2_(w2[jj], hq[jj], a2a);
                    }
                }
            }
            float acc0 = a0a + a0b, acc1 = a1a + a1b, acc2 = a2a + a2b;
            acc0 += __shfl_xor(acc0, 1);
            acc1 += __shfl_xor(acc1, 1);
            acc2 += __shfl_xor(acc2, 1);

            float r = sigmoid_(xr + acc0 + bias[0]);
            float z = sigmoid_(xz + acc1 + bias[1]);
            float n = tanh_(xn + r * (acc2 + bias[2]));
            float hnew = (1.0f - z) * n + z * hold;

            if (u == 0) hh[(t + 1) & 1][g] = (_Float16)hnew;
            else        hout[((long)b * TT + t) * HH + g] = __float2bfloat16(hnew);
            BARRIER_LDS();   // next h buffer ready; one barrier per step

            hold = hnew;
        }
    }
}

// ---------------------------------------------------------------------------
// Kernel C: LM head GEMM. C[2048,50257] = A[2048,256] * B[50304,256]^T, bf16
// MFMA 16x16x32, BM=BN=128, BK=64, 256 threads (r8 config).
// ROUND-10 FIX: LDS-transposed epilogue. The old epilogue emitted 64 scalar
// global_store_dword per thread; per instruction the wave wrote 4 scattered
// 64B row-segments -> ~2.5TB/s effective (partial L2-line RMW), which is the
// entire 165us (and why all B-side tilings were null: B reads hide under
// write stalls). New epilogue: each wave transposes its 64x64 tile through a
// wave-private LDS slice (reusing As/Bs after a sync; row stride 68 floats
// kills bank conflicts) and stores dwordx4 -> 4 x 256B contiguous segments
// per instruction, 16 stores/thread. LDS still 32KB -> occupancy unchanged.
// ---------------------------------------------------------------------------
__global__ __launch_bounds__(256) void k_head(
    const __hip_bfloat16* __restrict__ Ah, const __hip_bfloat16* __restrict__ Bw,
    float* __restrict__ out)
{
    __shared__ char smem[32768];
    unsigned short* As = (unsigned short*)smem;             // 16 KB
    unsigned short* Bs = (unsigned short*)(smem + 16384);   // 16 KB

    const int i    = threadIdx.x;
    const int wave = i >> 6, lane = i & 63;
    const int quad = lane >> 4, mr = lane & 15;

    // XCD-aligned tile assignment: lid%8 == ntile%8 (bijective over valid tiles)
    const int lid = blockIdx.x;          // [0, 6400)
    const int xq  = lid & 7;
    const int j   = lid >> 3;            // [0, 800)
    const int nt  = xq + 8 * (j % 50);   // n-tile, nt%8 == lid%8
    if (nt >= 393) return;               // 112 pad blocks idle
    const int m0  = (j / 50) * 128;
    const int n0  = nt * 128;

    const int wm0  = (wave >> 1) * 64;
    const int wn0  = (wave & 1) * 64;

    f32x4 acc[4][4];
#pragma unroll
    for (int a = 0; a < 4; ++a)
#pragma unroll
        for (int c = 0; c < 4; ++c) acc[a][c] = (f32x4){0.f, 0.f, 0.f, 0.f};

    const uint4* Ag = (const uint4*)Ah;   // row = 32 uint4 (256 bf16)
    const uint4* Bg = (const uint4*)Bw;
    uint4* Asv = (uint4*)As;
    uint4* Bsv = (uint4*)Bs;

    // Segment seg = c*4 + wave covers LDS slots [seg*64, seg*64+64).
    const uint4* agp[4]; const uint4* bgp[4];
    uint4* alds[4]; uint4* blds[4];
#pragma unroll
    for (int c = 0; c < 4; ++c) {
        int seg   = c * 4 + wave;
        int row   = seg * 8 + (lane >> 3);
        int chunk = (lane & 7) ^ (row & 7);
        agp[c] = Ag + (long)(m0 + row) * 32 + chunk;
        bgp[c] = Bg + (long)(n0 + row) * 32 + chunk;
        alds[c] = Asv + seg * 64;   // + lane*16B implicit in global_load_lds
        blds[c] = Bsv + seg * 64;
    }

    for (int ks = 0; ks < 4; ++ks) {
        __syncthreads();   // previous iteration's LDS readers done
#pragma unroll
        for (int c = 0; c < 4; ++c) async_copy16(agp[c] + ks * 8, alds[c]);
#pragma unroll
        for (int c = 0; c < 4; ++c) async_copy16(bgp[c] + ks * 8, blds[c]);
        __syncthreads();   // compiler emits s_waitcnt vmcnt(0) before barrier

#pragma unroll
        for (int kk = 0; kk < 2; ++kk) {
            bf16x8 af[4], bf[4];
#pragma unroll
            for (int wmi = 0; wmi < 4; ++wmi) {
                int row  = wm0 + wmi * 16 + mr;
                int slot = (kk * 4 + quad) ^ (row & 7);
                af[wmi] = *(const bf16x8*)&As[(row * 8 + slot) * 8];
            }
#pragma unroll
            for (int wni = 0; wni < 4; ++wni) {
                int row  = wn0 + wni * 16 + mr;
                int slot = (kk * 4 + quad) ^ (row & 7);
                bf[wni] = *(const bf16x8*)&Bs[(row * 8 + slot) * 8];
            }
#pragma unroll
            for (int wmi = 0; wmi < 4; ++wmi)
#pragma unroll
                for (int wni = 0; wni < 4; ++wni)
                    acc[wmi][wni] = __builtin_amdgcn_mfma_f32_16x16x32_bf16(
                        af[wmi], bf[wni], acc[wmi][wni], 0, 0, 0);
        }
    }

    // -------- LDS-transposed epilogue (wave-private 16x68 f32 slice) --------
    __syncthreads();   // all waves done reading As/Bs before we overwrite
    float* cst = (float*)smem + wave * (16 * 68);   // 4352B/wave, 17.4KB total

#pragma unroll
    for (int wmi = 0; wmi < 4; ++wmi) {
        // scatter this wmi's 16x64 sub-tile into the wave slice
#pragma unroll
        for (int wni = 0; wni < 4; ++wni)
#pragma unroll
            for (int rr = 0; rr < 4; ++rr)
                cst[(quad * 4 + rr) * 68 + wni * 16 + mr] = acc[wmi][wni][rr];
        asm volatile("s_waitcnt lgkmcnt(0)" ::: "memory");   // wave-local sync

        // read back row-major, store 16B/lane = 256B contiguous per row
#pragma unroll
        for (int it = 0; it < 4; ++it) {
            int row = it * 4 + (lane >> 4);     // [0,16)
            int cb  = (lane & 15) * 4;          // [0,64)
            f32x4 v = *(const f32x4*)&cst[row * 68 + cb];
            long m = m0 + wm0 + wmi * 16 + row;
            long n = n0 + wn0 + cb;
            if (n + 3 < V) {
                *(f32x4*)&out[m * (long)V + n] = v;
            } else {
#pragma unroll
                for (int e = 0; e < 4; ++e)
                    if (n + e < V) out[m * (long)V + n + e] = v[e];
            }
        }
        asm volatile("s_waitcnt lgkmcnt(0)" ::: "memory");   // reads done before next overwrite
    }
}

// ---------------------------------------------------------------------------
extern "C" void kernel_launch(void* const* d_in, const int* in_sizes, int n_in,
                              void* d_out, int out_size, void* d_ws, size_t ws_size,
                              hipStream_t stream) {
    const int*   ids   = (const int*)d_in[0];
    const float* embed = (const float*)d_in[1];
    const float* W_ih  = (const float*)d_in[2];
    const float* b_ih  = (const float*)d_in[3];
    const float* W_hh  = (const float*)d_in[4];
    const float* b_hh  = (const float*)d_in[5];
    const float* W_out = (const float*)d_in[6];
    float* out = (float*)d_out;

    // workspace layout (ws re-poisoned each launch; everything rewritten here)
    char* ws = (char*)d_ws;
    float*          gx   = (float*)ws;                          // 2048*768*4   = 6,291,456 B
    __hip_bfloat16* hbf  = (__hip_bfloat16*)(ws + 6291456);     // 2048*256*2   = 1,048,576 B
    __hip_bfloat16* wbf  = (__hip_bfloat16*)(ws + 7340032);     // 50304*256*2  = 25,755,648 B
    _Float16*       wh16 = (_Float16*)(ws + 33095680);          // 768*256*2    = 393,216 B

    k_prep<<<6640, 256, 0, stream>>>(ids, embed, W_ih, b_ih, gx, W_out, wbf, W_hh, wh16);
    k_gru<<<16, 512, 0, stream>>>(gx, wh16, b_hh, hbf);
    k_head<<<6400, 256, 0, stream>>>(hbf, wbf, out);
}